// Round 1
// baseline (607.240 us; speedup 1.0000x reference)
//
#include <hip/hip_runtime.h>

// fp16 fragment/accumulator types for gfx950 MFMA
typedef _Float16 h8 __attribute__((ext_vector_type(8)));
typedef _Float16 h4 __attribute__((ext_vector_type(4)));
typedef float f4 __attribute__((ext_vector_type(4)));

#define MFMA16(a, b, c) __builtin_amdgcn_mfma_f32_16x16x32_f16((a), (b), (c), 0, 0, 0)

// ---------------- fp32 -> fp16 elementwise convert ----------------
__global__ __launch_bounds__(256) void cvt_f32_f16(const float* __restrict__ in,
                                                   _Float16* __restrict__ out, int n) {
  int i = (blockIdx.x * 256 + threadIdx.x) * 4;
  if (i < n) {
    const float4 v = *(const float4*)(in + i);
    h4 o;
    o[0] = (_Float16)v.x; o[1] = (_Float16)v.y; o[2] = (_Float16)v.z; o[3] = (_Float16)v.w;
    *(h4*)(out + i) = o;
  }
}

// ---------------- transpose+convert: W[K][N] f32 -> Wt[N][K] f16 ----------------
__global__ __launch_bounds__(256) void transpose_cvt(const float* __restrict__ W,
                                                     _Float16* __restrict__ Wt, int K, int N) {
  __shared__ _Float16 t[64][66];  // 66: bank-conflict-free column reads
  int n0 = blockIdx.x * 64, k0 = blockIdx.y * 64;
  int c = threadIdx.x & 63, r0 = threadIdx.x >> 6;
  for (int i = 0; i < 16; i++) {
    int r = r0 * 16 + i;
    t[r][c] = (_Float16)W[(size_t)(k0 + r) * N + n0 + c];
  }
  __syncthreads();
  for (int i = 0; i < 16; i++) {
    int r = r0 * 16 + i;
    Wt[(size_t)(n0 + r) * K + k0 + c] = t[c][r];
  }
}

// ---------------- GEMM: C[M][N] = A[M][K] @ Bt[N][K]^T + bias ----------------
// MODE 0: QKV projection epilogue -> scatter into q[b,h,s,d], k[b,h,s,d], vt[b,h,d,s] (f16)
// MODE 1: output projection -> fp32 out[M][N]
// Block: 256 thr (4 waves, 2x2), tile 128x128, BK=32.
template <int MODE>
__global__ __launch_bounds__(256) void gemm_bt(const _Float16* __restrict__ A,
                                               const _Float16* __restrict__ Bt,
                                               const float* __restrict__ bias, int K,
                                               _Float16* __restrict__ qp, _Float16* __restrict__ kp,
                                               _Float16* __restrict__ vtp, float* __restrict__ outp,
                                               int N) {
  __shared__ _Float16 As[128][40];  // stride 40 f16 = 80B: b128 reads hit the 8-phase minimum
  __shared__ _Float16 Bs[128][40];
  const int m0 = blockIdx.y * 128, n0 = blockIdx.x * 128;
  const int tid = threadIdx.x;
  const int w = tid >> 6, lane = tid & 63, quad = lane >> 4, l16 = lane & 15;
  const int wm = (w >> 1) * 64, wn = (w & 1) * 64;

  f4 acc[4][4] = {};
  for (int k0 = 0; k0 < K; k0 += 32) {
    __syncthreads();  // protect previous iteration's fragment reads
    for (int i = 0; i < 2; i++) {
      int idx = tid + 256 * i;  // 512 chunks of 8 f16 per tile
      int r = idx >> 2, cc = (idx & 3) * 8;
      *(h8*)(&As[r][cc]) = *(const h8*)(A + (size_t)(m0 + r) * K + k0 + cc);
      *(h8*)(&Bs[r][cc]) = *(const h8*)(Bt + (size_t)(n0 + r) * K + k0 + cc);
    }
    __syncthreads();
    h8 af[4], bf[4];
    for (int mi = 0; mi < 4; mi++) af[mi] = *(h8*)(&As[wm + mi * 16 + l16][quad * 8]);
    for (int ni = 0; ni < 4; ni++) bf[ni] = *(h8*)(&Bs[wn + ni * 16 + l16][quad * 8]);
    for (int mi = 0; mi < 4; mi++)
      for (int ni = 0; ni < 4; ni++) acc[mi][ni] = MFMA16(af[mi], bf[ni], acc[mi][ni]);
  }

  // Epilogue. C element (row = quad*4+r, col = l16) within each 16x16 tile [m89-verified].
  for (int mi = 0; mi < 4; mi++)
    for (int ni = 0; ni < 4; ni++) {
      int gm_base = m0 + wm + mi * 16 + quad * 4;
      int gn = n0 + wn + ni * 16 + l16;
      float bv = bias[gn];
      for (int r = 0; r < 4; r++) {
        int gm = gm_base + r;
        float v = acc[mi][ni][r] + bv;
        if constexpr (MODE == 0) {
          // gn in [0,6144): which = q/k/v, h = head, d = dim. Block-uniform which,h.
          int which = gn >> 11, h = (gn >> 7) & 15, d = gn & 127;
          int b = gm >> 11, s = gm & 2047;
          size_t hb = (size_t)b * 16 + h;
          if (which == 0)
            qp[(hb * 2048 + s) * 128 + d] = (_Float16)v;
          else if (which == 1)
            kp[(hb * 2048 + s) * 128 + d] = (_Float16)v;
          else
            vtp[(hb * 128 + d) * 2048 + s] = (_Float16)v;
        } else {
          outp[(size_t)gm * N + gn] = v;
        }
      }
    }
}

// ---------------- fused causal ALiBi attention (flash-style) ----------------
// grid: (S/64, NH, B). Block 256 = 4 waves; wave w owns 16 q-rows.
// NOTE reference applies NO 1/sqrt(d) scaling; mask = slope_h * (j-i) for j<=i else -inf,
// slope_h = 2^(-h/2) (NUM_HEADS=16 > 8 branch).
__global__ __launch_bounds__(256) void attn_kernel(const _Float16* __restrict__ Q,
                                                   const _Float16* __restrict__ Kg,
                                                   const _Float16* __restrict__ Vt,
                                                   _Float16* __restrict__ ctx) {
  __shared__ _Float16 Ks[32][136];    // K rows [j][d], pad to 136
  __shared__ _Float16 Vs[128][40];    // V^T rows [d][j], pad to 40
  __shared__ _Float16 Pl[4][16][40];  // per-wave P round-trip (C-layout -> A-layout)

  const int qt = blockIdx.x, h = blockIdx.y, b = blockIdx.z;
  const int tid = threadIdx.x, w = tid >> 6, lane = tid & 63, quad = lane >> 4, l16 = lane & 15;
  const size_t hb = (size_t)b * 16 + h;
  const _Float16* Qh = Q + hb * 2048 * 128;
  const _Float16* Kh = Kg + hb * 2048 * 128;
  const _Float16* Vh = Vt + hb * 128 * 2048;
  const int qbase = qt * 64 + w * 16;
  const float slope = exp2f(-0.5f * (float)h);
  const float L2E = 1.44269504088896f;

  // Q fragments: A[m=l16][k=quad*8+j] [m120-verified layout]
  h8 aq[4];
  for (int t4 = 0; t4 < 4; t4++)
    aq[t4] = *(const h8*)(Qh + (size_t)(qbase + l16) * 128 + t4 * 32 + quad * 8);

  f4 o[8] = {};
  float m_i[4], l_i[4];
  for (int r = 0; r < 4; r++) { m_i[r] = -__builtin_inff(); l_i[r] = 0.f; }

  const int jend = qt * 64 + 63;  // block-uniform trip count
  for (int j0 = 0; j0 <= jend; j0 += 32) {
    __syncthreads();  // previous tile's fragment reads done before overwrite
    for (int i = 0; i < 2; i++) {
      int idx = tid + 256 * i;
      int r = idx >> 4, cc = (idx & 15) * 8;  // K: 32 rows x 128 cols
      *(h8*)(&Ks[r][cc]) = *(const h8*)(Kh + (size_t)(j0 + r) * 128 + cc);
      int r2 = idx >> 2, c2 = (idx & 3) * 8;  // V^T: 128 rows x 32 cols
      *(h8*)(&Vs[r2][c2]) = *(const h8*)(Vh + (size_t)r2 * 2048 + j0 + c2);
    }
    __syncthreads();
    if (j0 > qbase + 15) continue;  // wave fully masked; no barriers below

    // S = Q K^T : two 16x16 C-frags covering 32 j-columns
    f4 sc[2] = {};
    for (int hf = 0; hf < 2; hf++)
      for (int t4 = 0; t4 < 4; t4++) {
        h8 bk = *(h8*)(&Ks[hf * 16 + l16][t4 * 32 + quad * 8]);
        sc[hf] = MFMA16(aq[t4], bk, sc[hf]);
      }
    // causal + alibi in C-layout
    for (int hf = 0; hf < 2; hf++)
      for (int r = 0; r < 4; r++) {
        int i = qbase + quad * 4 + r;
        int j = j0 + hf * 16 + l16;
        float s = sc[hf][r];
        sc[hf][r] = (j <= i) ? (s + slope * (float)(j - i)) : -__builtin_inff();
      }
    // online softmax: row stats live across the 16-lane group (one quad)
    float m_new[4], alpha[4];
    for (int r = 0; r < 4; r++) {
      float v = fmaxf(sc[0][r], sc[1][r]);
      v = fmaxf(v, __shfl_xor(v, 1));
      v = fmaxf(v, __shfl_xor(v, 2));
      v = fmaxf(v, __shfl_xor(v, 4));
      v = fmaxf(v, __shfl_xor(v, 8));
      m_new[r] = fmaxf(m_i[r], v);
      alpha[r] = exp2f((m_i[r] - m_new[r]) * L2E);
    }
    for (int hf = 0; hf < 2; hf++)
      for (int r = 0; r < 4; r++) sc[hf][r] = exp2f((sc[hf][r] - m_new[r]) * L2E);
    for (int r = 0; r < 4; r++) {
      float sum = sc[0][r] + sc[1][r];
      sum += __shfl_xor(sum, 1);
      sum += __shfl_xor(sum, 2);
      sum += __shfl_xor(sum, 4);
      sum += __shfl_xor(sum, 8);
      l_i[r] = l_i[r] * alpha[r] + sum;
      m_i[r] = m_new[r];
    }
    for (int nt = 0; nt < 8; nt++)
      for (int r = 0; r < 4; r++) o[nt][r] *= alpha[r];
    // P: C-layout -> A-layout via per-wave LDS (wave-internal; DS ops in-order per wave)
    for (int hf = 0; hf < 2; hf++)
      for (int r = 0; r < 4; r++) Pl[w][quad * 4 + r][hf * 16 + l16] = (_Float16)sc[hf][r];
    asm volatile("s_waitcnt lgkmcnt(0)" ::: "memory");
    h8 ap = *(h8*)(&Pl[w][l16][quad * 8]);
    // O += P V : 8 n-tiles over D=128
    for (int nt = 0; nt < 8; nt++) {
      h8 bv = *(h8*)(&Vs[nt * 16 + l16][quad * 8]);
      o[nt] = MFMA16(ap, bv, o[nt]);
    }
  }

  // epilogue: normalize, write ctx[b, s, h*128+d] (f16)
  for (int r = 0; r < 4; r++) {
    float inv = 1.0f / l_i[r];
    int i = qbase + quad * 4 + r;
    size_t row = (size_t)b * 2048 + i;
    for (int nt = 0; nt < 8; nt++)
      ctx[row * 2048 + h * 128 + nt * 16 + l16] = (_Float16)(o[nt][r] * inv);
  }
}

extern "C" void kernel_launch(void* const* d_in, const int* in_sizes, int n_in, void* d_out,
                              int out_size, void* d_ws, size_t ws_size, hipStream_t stream) {
  const float* x = (const float*)d_in[0];      // [2,2048,2048]
  const float* qkv_w = (const float*)d_in[1];  // [2048,6144]
  const float* qkv_b = (const float*)d_in[2];  // [6144]
  const float* out_w = (const float*)d_in[3];  // [2048,2048]
  const float* out_b = (const float*)d_in[4];  // [2048]
  float* out = (float*)d_out;                  // [4096,2048] f32

  char* ws = (char*)d_ws;
  if (ws_size < 117440512u) return;  // need 112 MiB
  _Float16* xb  = (_Float16*)(ws + 0);          // 16 MiB  [4096][2048]
  _Float16* wqt = (_Float16*)(ws + 16777216);   // 24 MiB  [6144][2048]
  _Float16* wot = (_Float16*)(ws + 41943040);   // 8 MiB   [2048][2048]
  _Float16* q   = (_Float16*)(ws + 50331648);   // 16 MiB  [b,h,s,d]
  _Float16* k   = (_Float16*)(ws + 67108864);   // 16 MiB  [b,h,s,d]
  _Float16* vt  = (_Float16*)(ws + 83886080);   // 16 MiB  [b,h,d,s]
  _Float16* ctx = (_Float16*)(ws + 100663296);  // 16 MiB  [4096][2048]

  cvt_f32_f16<<<8192, 256, 0, stream>>>(x, xb, 8388608);
  transpose_cvt<<<dim3(96, 32), 256, 0, stream>>>(qkv_w, wqt, 2048, 6144);
  transpose_cvt<<<dim3(32, 32), 256, 0, stream>>>(out_w, wot, 2048, 2048);
  gemm_bt<0><<<dim3(48, 32), 256, 0, stream>>>(xb, wqt, qkv_b, 2048, q, k, vt, nullptr, 6144);
  attn_kernel<<<dim3(32, 16, 2), 256, 0, stream>>>(q, k, vt, ctx);
  gemm_bt<1><<<dim3(16, 32), 256, 0, stream>>>(ctx, wot, out_b, 2048, nullptr, nullptr, nullptr,
                                               out, 2048);
}

// Round 2
// 475.677 us; speedup vs baseline: 1.2766x; 1.2766x over previous
//
#include <hip/hip_runtime.h>

typedef _Float16 h8 __attribute__((ext_vector_type(8)));
typedef _Float16 h4 __attribute__((ext_vector_type(4)));
typedef float f4 __attribute__((ext_vector_type(4)));

#define MFMA16(a, b, c) __builtin_amdgcn_mfma_f32_16x16x32_f16((a), (b), (c), 0, 0, 0)
#define AS1 __attribute__((address_space(1)))
#define AS3 __attribute__((address_space(3)))

static __device__ __forceinline__ void load_lds16(const _Float16* g, _Float16* l) {
  // 16B per lane, LDS dest = wave-uniform base + lane*16 [m97]
  __builtin_amdgcn_global_load_lds((const AS1 void*)g, (AS3 void*)l, 16, 0, 0);
}

// ---------------- fp32 -> fp16 elementwise convert ----------------
__global__ __launch_bounds__(256) void cvt_f32_f16(const float* __restrict__ in,
                                                   _Float16* __restrict__ out, int n) {
  int i = (blockIdx.x * 256 + threadIdx.x) * 4;
  if (i < n) {
    const float4 v = *(const float4*)(in + i);
    h4 o;
    o[0] = (_Float16)v.x; o[1] = (_Float16)v.y; o[2] = (_Float16)v.z; o[3] = (_Float16)v.w;
    *(h4*)(out + i) = o;
  }
}

// ---------------- transpose+convert: W[K][N] f32 -> Wt[N][K] f16 ----------------
__global__ __launch_bounds__(256) void transpose_cvt(const float* __restrict__ W,
                                                     _Float16* __restrict__ Wt, int K, int N) {
  __shared__ _Float16 t[64][66];
  int n0 = blockIdx.x * 64, k0 = blockIdx.y * 64;
  int c = threadIdx.x & 63, r0 = threadIdx.x >> 6;
  for (int i = 0; i < 16; i++) {
    int r = r0 * 16 + i;
    t[r][c] = (_Float16)W[(size_t)(k0 + r) * N + n0 + c];
  }
  __syncthreads();
  for (int i = 0; i < 16; i++) {
    int r = r0 * 16 + i;
    Wt[(size_t)(n0 + r) * K + k0 + c] = t[c][r];
  }
}

// ---------------- GEMM (m97-style): C[M][N] = A[M][K] @ Bt[N][K]^T + bias ----------------
// global_load_lds width=16 staging into unpadded BK=32 LDS with XOR chunk swizzle.
// LDS slot s (16B chunks): row r = s>>2, phys chunk = s&3, logical chunk = (s&3) ^ ((r>>1)&3).
// MODE 0: QKV epilogue -> q[b,h,s,d], k[b,h,s,d], vt[b,h,d,s] (f16); MODE 1: fp32 out.
template <int MODE>
__global__ __launch_bounds__(256) void gemm_bt(const _Float16* __restrict__ A,
                                               const _Float16* __restrict__ Bt,
                                               const float* __restrict__ bias, int K,
                                               _Float16* __restrict__ qp, _Float16* __restrict__ kp,
                                               _Float16* __restrict__ vtp, float* __restrict__ outp,
                                               int N) {
  __shared__ _Float16 As[128 * 32];
  __shared__ _Float16 Bs[128 * 32];
  const int m0 = blockIdx.y * 128, n0 = blockIdx.x * 128;
  const int tid = threadIdx.x;
  const int w = tid >> 6, lane = tid & 63, quad = lane >> 4, l16 = lane & 15;
  const int wm = (w >> 1) * 64, wn = (w & 1) * 64;

  // two staging calls per operand per wave; per-lane global source for swizzled slot
  const int s0 = w * 128 + lane, s1 = s0 + 64;
  const int r0 = s0 >> 2, c0 = (s0 & 3) ^ ((r0 >> 1) & 3);
  const int r1 = s1 >> 2, c1 = (s1 & 3) ^ ((r1 >> 1) & 3);
  const _Float16* a0 = A + (size_t)(m0 + r0) * K + c0 * 8;
  const _Float16* a1 = A + (size_t)(m0 + r1) * K + c1 * 8;
  const _Float16* b0 = Bt + (size_t)(n0 + r0) * K + c0 * 8;
  const _Float16* b1 = Bt + (size_t)(n0 + r1) * K + c1 * 8;
  _Float16* lA0 = As + w * 1024;  // wave-uniform LDS bases
  _Float16* lA1 = As + w * 1024 + 512;
  _Float16* lB0 = Bs + w * 1024;
  _Float16* lB1 = Bs + w * 1024 + 512;

  f4 acc[4][4] = {};
  for (int k0 = 0; k0 < K; k0 += 32) {
    __syncthreads();  // previous iteration's fragment reads done
    load_lds16(a0 + k0, lA0);
    load_lds16(a1 + k0, lA1);
    load_lds16(b0 + k0, lB0);
    load_lds16(b1 + k0, lB1);
    __syncthreads();  // implies vmcnt(0) drain of global_load_lds
    h8 af[4], bf[4];
    for (int mi = 0; mi < 4; mi++) {
      int r = wm + mi * 16 + l16;
      af[mi] = *(h8*)(&As[(r * 4 + (quad ^ ((r >> 1) & 3))) * 8]);
    }
    for (int ni = 0; ni < 4; ni++) {
      int r = wn + ni * 16 + l16;
      bf[ni] = *(h8*)(&Bs[(r * 4 + (quad ^ ((r >> 1) & 3))) * 8]);
    }
    for (int mi = 0; mi < 4; mi++)
      for (int ni = 0; ni < 4; ni++) acc[mi][ni] = MFMA16(af[mi], bf[ni], acc[mi][ni]);
  }

  // Epilogue. C element (row = quad*4+r, col = l16) per 16x16 tile [m89-verified].
  for (int mi = 0; mi < 4; mi++)
    for (int ni = 0; ni < 4; ni++) {
      int gm_base = m0 + wm + mi * 16 + quad * 4;
      int gn = n0 + wn + ni * 16 + l16;
      float bv = bias[gn];
      for (int r = 0; r < 4; r++) {
        int gm = gm_base + r;
        float v = acc[mi][ni][r] + bv;
        if constexpr (MODE == 0) {
          int which = gn >> 11, h = (gn >> 7) & 15, d = gn & 127;
          int b = gm >> 11, s = gm & 2047;
          size_t hb = (size_t)b * 16 + h;
          if (which == 0)
            qp[(hb * 2048 + s) * 128 + d] = (_Float16)v;
          else if (which == 1)
            kp[(hb * 2048 + s) * 128 + d] = (_Float16)v;
          else
            vtp[(hb * 128 + d) * 2048 + s] = (_Float16)v;
        } else {
          outp[(size_t)gm * N + gn] = v;
        }
      }
    }
}

// ---------------- fused causal ALiBi attention (flash-style, balanced+prefetched) ----------------
// grid: (16, NH, B); block px handles q-tiles {31-px, px} sequentially -> uniform 33 j-iters.
// 256 thr = 4 waves, wave owns 16 q-rows; j-tile 64; next K/V tile prefetched into VGPRs
// while current tile computes (hides global latency behind MFMA+softmax).
__global__ __launch_bounds__(256) void attn_kernel(const _Float16* __restrict__ Q,
                                                   const _Float16* __restrict__ Kg,
                                                   const _Float16* __restrict__ Vt,
                                                   _Float16* __restrict__ ctx) {
  __shared__ _Float16 Ks[64][136];    // [j][d], stride 272B = 17 x 16B units -> conflict-free
  __shared__ _Float16 Vs[128][72];    // [d][j], stride 144B = 9 units -> conflict-free
  __shared__ _Float16 Pl[4][16][72];  // per-wave P round-trip (C-layout -> A-layout)

  const int px = blockIdx.x, h = blockIdx.y, b = blockIdx.z;
  const int tid = threadIdx.x, w = tid >> 6, lane = tid & 63, quad = lane >> 4, l16 = lane & 15;
  const size_t hb = (size_t)b * 16 + h;
  const _Float16* Qh = Q + hb * (size_t)(2048 * 128);
  const _Float16* Kh = Kg + hb * (size_t)(2048 * 128);
  const _Float16* Vh = Vt + hb * (size_t)(2048 * 128);
  const float slope = exp2f(-0.5f * (float)h);
  const float L2E = 1.44269504088896f;
  const float NEG = -3.0e38f;

  for (int phase = 0; phase < 2; phase++) {
    const int t = (phase == 0) ? (31 - px) : px;
    const int qbase = t * 64 + w * 16;

    // Q fragments: A[m=l16][k=quad*8+j] [m120-verified]
    h8 aq[4];
    for (int t4 = 0; t4 < 4; t4++)
      aq[t4] = *(const h8*)(Qh + (size_t)(qbase + l16) * 128 + t4 * 32 + quad * 8);

    f4 o[8] = {};
    float m_i[4], l_i[4];
    for (int r = 0; r < 4; r++) { m_i[r] = NEG; l_i[r] = 0.f; }

    const int jlast = t * 64;
    // prefetch tile 0 into registers
    h8 pk[4], pv[4];
    for (int i = 0; i < 4; i++) {
      int id = tid + 256 * i;
      pk[i] = *(const h8*)(Kh + (size_t)(id >> 4) * 128 + (id & 15) * 8);
      pv[i] = *(const h8*)(Vh + (size_t)(id >> 3) * 2048 + (id & 7) * 8);
    }

    for (int j0 = 0; j0 <= jlast; j0 += 64) {
      __syncthreads();  // previous tile's LDS readers done
      for (int i = 0; i < 4; i++) {
        int id = tid + 256 * i;
        *(h8*)(&Ks[id >> 4][(id & 15) * 8]) = pk[i];
        *(h8*)(&Vs[id >> 3][(id & 7) * 8]) = pv[i];
      }
      __syncthreads();
      if (j0 < jlast) {  // issue next tile's loads; latency overlaps compute below
        int jn = j0 + 64;
        for (int i = 0; i < 4; i++) {
          int id = tid + 256 * i;
          pk[i] = *(const h8*)(Kh + (size_t)(jn + (id >> 4)) * 128 + (id & 15) * 8);
          pv[i] = *(const h8*)(Vh + (size_t)(id >> 3) * 2048 + jn + (id & 7) * 8);
        }
      }
      if (j0 > qbase + 15) continue;  // wave fully masked (no barriers below)

      // S = Q K^T : four 16x16 C-frags covering 64 j-columns
      f4 sc[4] = {};
      for (int jf = 0; jf < 4; jf++)
        for (int t4 = 0; t4 < 4; t4++) {
          h8 bk = *(h8*)(&Ks[jf * 16 + l16][t4 * 32 + quad * 8]);
          sc[jf] = MFMA16(aq[t4], bk, sc[jf]);
        }
      // causal + alibi in C-layout (row=quad*4+r, col=l16)
      for (int jf = 0; jf < 4; jf++) {
        int j = j0 + jf * 16 + l16;
        for (int r = 0; r < 4; r++) {
          int i = qbase + quad * 4 + r;
          float s = sc[jf][r];
          sc[jf][r] = (j <= i) ? (s + slope * (float)(j - i)) : NEG;
        }
      }
      // online softmax: row stats across the 16-lane group
      float m_new[4], alpha[4];
      for (int r = 0; r < 4; r++) {
        float v = fmaxf(fmaxf(sc[0][r], sc[1][r]), fmaxf(sc[2][r], sc[3][r]));
        v = fmaxf(v, __shfl_xor(v, 1));
        v = fmaxf(v, __shfl_xor(v, 2));
        v = fmaxf(v, __shfl_xor(v, 4));
        v = fmaxf(v, __shfl_xor(v, 8));
        m_new[r] = fmaxf(m_i[r], v);
        alpha[r] = exp2f((m_i[r] - m_new[r]) * L2E);
      }
      for (int jf = 0; jf < 4; jf++)
        for (int r = 0; r < 4; r++) sc[jf][r] = exp2f((sc[jf][r] - m_new[r]) * L2E);
      for (int r = 0; r < 4; r++) {
        float sum = (sc[0][r] + sc[1][r]) + (sc[2][r] + sc[3][r]);
        sum += __shfl_xor(sum, 1);
        sum += __shfl_xor(sum, 2);
        sum += __shfl_xor(sum, 4);
        sum += __shfl_xor(sum, 8);
        l_i[r] = l_i[r] * alpha[r] + sum;
        m_i[r] = m_new[r];
      }
      for (int nt = 0; nt < 8; nt++)
        for (int r = 0; r < 4; r++) o[nt][r] *= alpha[r];
      // P: C-layout -> A-layout via per-wave LDS (wave-internal, DS in-order)
      for (int jf = 0; jf < 4; jf++)
        for (int r = 0; r < 4; r++) Pl[w][quad * 4 + r][jf * 16 + l16] = (_Float16)sc[jf][r];
      asm volatile("s_waitcnt lgkmcnt(0)" ::: "memory");
      h8 ap0 = *(h8*)(&Pl[w][l16][quad * 8]);
      h8 ap1 = *(h8*)(&Pl[w][l16][32 + quad * 8]);
      // O += P V : 8 n-tiles over D=128, two k-halves
      for (int nt = 0; nt < 8; nt++) {
        h8 bv0 = *(h8*)(&Vs[nt * 16 + l16][quad * 8]);
        h8 bv1 = *(h8*)(&Vs[nt * 16 + l16][32 + quad * 8]);
        o[nt] = MFMA16(ap0, bv0, o[nt]);
        o[nt] = MFMA16(ap1, bv1, o[nt]);
      }
    }

    // epilogue: normalize, write ctx[b, s, h*128+d] (f16)
    for (int r = 0; r < 4; r++) {
      float inv = 1.0f / l_i[r];
      int i = qbase + quad * 4 + r;
      size_t row = (size_t)b * 2048 + i;
      for (int nt = 0; nt < 8; nt++)
        ctx[row * 2048 + h * 128 + nt * 16 + l16] = (_Float16)(o[nt][r] * inv);
    }
  }
}

extern "C" void kernel_launch(void* const* d_in, const int* in_sizes, int n_in, void* d_out,
                              int out_size, void* d_ws, size_t ws_size, hipStream_t stream) {
  const float* x = (const float*)d_in[0];      // [2,2048,2048]
  const float* qkv_w = (const float*)d_in[1];  // [2048,6144]
  const float* qkv_b = (const float*)d_in[2];  // [6144]
  const float* out_w = (const float*)d_in[3];  // [2048,2048]
  const float* out_b = (const float*)d_in[4];  // [2048]
  float* out = (float*)d_out;                  // [4096,2048] f32

  char* ws = (char*)d_ws;
  if (ws_size < 117440512u) return;  // need 112 MiB
  _Float16* xb  = (_Float16*)(ws + 0);          // 16 MiB  [4096][2048]
  _Float16* wqt = (_Float16*)(ws + 16777216);   // 24 MiB  [6144][2048]
  _Float16* wot = (_Float16*)(ws + 41943040);   // 8 MiB   [2048][2048]
  _Float16* q   = (_Float16*)(ws + 50331648);   // 16 MiB  [b,h,s,d]
  _Float16* k   = (_Float16*)(ws + 67108864);   // 16 MiB  [b,h,s,d]
  _Float16* vt  = (_Float16*)(ws + 83886080);   // 16 MiB  [b,h,d,s]
  _Float16* ctx = (_Float16*)(ws + 100663296);  // 16 MiB  [4096][2048]

  cvt_f32_f16<<<8192, 256, 0, stream>>>(x, xb, 8388608);
  transpose_cvt<<<dim3(96, 32), 256, 0, stream>>>(qkv_w, wqt, 2048, 6144);
  transpose_cvt<<<dim3(32, 32), 256, 0, stream>>>(out_w, wot, 2048, 2048);
  gemm_bt<0><<<dim3(48, 32), 256, 0, stream>>>(xb, wqt, qkv_b, 2048, q, k, vt, nullptr, 6144);
  attn_kernel<<<dim3(16, 16, 2), 256, 0, stream>>>(q, k, vt, ctx);
  gemm_bt<1><<<dim3(16, 32), 256, 0, stream>>>(ctx, wot, out_b, 2048, nullptr, nullptr, nullptr,
                                               out, 2048);
}